// Round 5
// baseline (319.114 us; speedup 1.0000x reference)
//
#include <hip/hip_runtime.h>
#include <math.h>

#define B_    4
#define CDIM  512
#define HEADS 8
#define HD    64
#define NN    4096
#define QSZ   ((size_t)B_*HEADS*NN*HD)   // 8388608 elements
// q scale folded with log2(e): 0.125 * 1.4426950408889634
#define SCALE_Q 0.18033688011112042f

typedef __attribute__((ext_vector_type(8))) short short8;   // 8 bf16
typedef __attribute__((ext_vector_type(4))) float f32x4;
typedef __attribute__((ext_vector_type(16))) float f32x16;
union U4S8 { uint4 u; short8 s; };

// RNE fp32 -> bf16
__device__ inline unsigned pk(float a, float b) {
    unsigned ua = __float_as_uint(a), ub = __float_as_uint(b);
    ua += 0x7FFFu + ((ua >> 16) & 1u);
    ub += 0x7FFFu + ((ub >> 16) & 1u);
    return (ua >> 16) | (ub & 0xFFFF0000u);
}
__device__ inline unsigned short bf16_1(float a) {
    unsigned ua = __float_as_uint(a);
    ua += 0x7FFFu + ((ua >> 16) & 1u);
    return (unsigned short)(ua >> 16);
}
// cheap round-half-up pack (positive inputs): 2 adds + 1 v_perm
__device__ inline unsigned pkru(float a, float b) {
    unsigned ua = __float_as_uint(a) + 0x8000u;
    unsigned ub = __float_as_uint(b) + 0x8000u;
    return __builtin_amdgcn_perm(ub, ua, 0x07060302);  // [hi16(ua) | hi16(ub)<<16]
}

__device__ inline void load_lds16(const unsigned short* g, unsigned short* l) {
    __builtin_amdgcn_global_load_lds(
        (const __attribute__((address_space(1))) unsigned int*)g,
        (__attribute__((address_space(3))) unsigned int*)l, 16, 0, 0);
}

// ------------------------------------------------------- weights -> bf16
__global__ void conv_w_kernel(const float* __restrict__ wq, const float* __restrict__ wp,
                              unsigned short* __restrict__ wqb, unsigned short* __restrict__ wpb) {
    int id = blockIdx.x * 256 + threadIdx.x;
    const float* src; unsigned short* dst; size_t off; float sc = 1.0f;
    if (id < 98304) { src = wq; dst = wqb; off = (size_t)id * 8; if (off < 262144) sc = SCALE_Q; }
    else            { src = wp; dst = wpb; off = (size_t)(id - 98304) * 8; }
    float4 a = *(const float4*)(src + off);
    float4 b = *(const float4*)(src + off + 4);
    uint4 u;
    u.x = pk(a.x * sc, a.y * sc); u.y = pk(a.z * sc, a.w * sc);
    u.z = pk(b.x * sc, b.y * sc); u.w = pk(b.z * sc, b.w * sc);
    *(uint4*)(dst + off) = u;
}

// ------------------------------------------------------- rope tables [j][n]
__global__ void rope_table_kernel(float* __restrict__ ct, float* __restrict__ st) {
    int id = blockIdx.x * 256 + threadIdx.x;
    int j = id >> 12, n = id & 4095;
    int i = j & 15;
    float pos = (j < 16) ? (float)(n >> 6) : (float)(n & 63);
    float freq = exp2f(-(float)i * 0.8304820237218406f);  // 10000^(-i/16)
    float ang = pos * freq;
    ct[id] = cosf(ang);
    st[id] = sinf(ang);
}

// ------------------------------------------------------- x transpose+convert
__global__ __launch_bounds__(256) void transpose_x_kernel(
        const float* __restrict__ x, unsigned short* __restrict__ xt) {
    __shared__ unsigned short T[64 * 72];
    int t = threadIdx.x;
    int b = blockIdx.z, c0 = blockIdx.y * 64, n0 = blockIdx.x * 64;
    const float* xb = x + ((size_t)b * CDIM + c0) * NN + n0;
    int crow = t >> 2, nseg = t & 3;
#pragma unroll
    for (int g = 0; g < 4; ++g) {
        float4 f = *(const float4*)(xb + (size_t)crow * NN + nseg * 16 + g * 4);
        int nb = nseg * 16 + g * 4;
        T[(nb + 0) * 72 + crow] = bf16_1(f.x);
        T[(nb + 1) * 72 + crow] = bf16_1(f.y);
        T[(nb + 2) * 72 + crow] = bf16_1(f.z);
        T[(nb + 3) * 72 + crow] = bf16_1(f.w);
    }
    __syncthreads();
    unsigned short* xo = xt + ((size_t)b * NN + n0) * CDIM + c0;
    int nrow = t >> 2, cseg = t & 3;
    uint4 u0 = *(uint4*)(T + nrow * 72 + cseg * 16);
    uint4 u1 = *(uint4*)(T + nrow * 72 + cseg * 16 + 8);
    *(uint4*)(xo + (size_t)nrow * CDIM + cseg * 16)     = u0;
    *(uint4*)(xo + (size_t)nrow * CDIM + cseg * 16 + 8) = u1;
}

// ------------------------------------------------------- qkv MFMA GEMM
__global__ __launch_bounds__(256, 2) void qkv_mfma_kernel(
        const unsigned short* __restrict__ xt, const unsigned short* __restrict__ wq,
        unsigned short* __restrict__ qbf, unsigned short* __restrict__ kbf,
        unsigned short* __restrict__ vt,
        const float* __restrict__ ct, const float* __restrict__ st) {
    __shared__ unsigned short smem[8192];
    int t = threadIdx.x;
    int lane = t & 63, w = t >> 6;
    int qlo = lane & 15, quad = lane >> 4;
    int b = blockIdx.z, o0 = blockIdx.y * 128, n0 = blockIdx.x * 128;
    const unsigned short* xb = xt + (size_t)b * NN * CDIM;
    int row = t >> 2, seg = t & 3;
    int wn = (w & 1) * 64, wo = (w >> 1) * 64;

    f32x4 acc[4][4];
#pragma unroll
    for (int i = 0; i < 4; ++i)
#pragma unroll
        for (int j = 0; j < 4; ++j) acc[i][j] = f32x4{0.f, 0.f, 0.f, 0.f};

    for (int k0 = 0; k0 < 512; k0 += 32) {
        __syncthreads();
        load_lds16(xb + (size_t)(n0 + row) * 512 + k0 + seg * 8,        smem + t * 8);
        load_lds16(xb + (size_t)(n0 + 64 + row) * 512 + k0 + seg * 8,   smem + 2048 + t * 8);
        load_lds16(wq + (size_t)(o0 + row) * 512 + k0 + seg * 8,        smem + 4096 + t * 8);
        load_lds16(wq + (size_t)(o0 + 64 + row) * 512 + k0 + seg * 8,   smem + 6144 + t * 8);
        __syncthreads();
        U4S8 af[4], bf[4];
#pragma unroll
        for (int mt = 0; mt < 4; ++mt)
            af[mt].u = *(const uint4*)(smem + (wn + 16 * mt + qlo) * 32 + quad * 8);
#pragma unroll
        for (int nt = 0; nt < 4; ++nt)
            bf[nt].u = *(const uint4*)(smem + 4096 + (wo + 16 * nt + qlo) * 32 + quad * 8);
#pragma unroll
        for (int mt = 0; mt < 4; ++mt)
#pragma unroll
            for (int nt = 0; nt < 4; ++nt)
                acc[mt][nt] = __builtin_amdgcn_mfma_f32_16x16x32_bf16(
                    af[mt].s, bf[nt].s, acc[mt][nt], 0, 0, 0);
    }

    int og = o0 + wo;
    int s = og >> 9;
    int h = (og & 511) >> 6;
    int bh = b * HEADS + h;
    if (s < 2) {
        unsigned short* dst = (s ? kbf : qbf) + (size_t)bh * NN * HD;
#pragma unroll
        for (int mt = 0; mt < 4; ++mt) {
            int nbase = n0 + wn + 16 * mt + 4 * quad;
#pragma unroll
            for (int ntp = 0; ntp < 2; ++ntp) {
                int j = 16 * ntp + qlo;
                float4 c4 = *(const float4*)(ct + (size_t)j * NN + nbase);
                float4 s4 = *(const float4*)(st + (size_t)j * NN + nbase);
                float cc[4] = {c4.x, c4.y, c4.z, c4.w};
                float ss[4] = {s4.x, s4.y, s4.z, s4.w};
#pragma unroll
                for (int r = 0; r < 4; ++r) {
                    float x1 = acc[mt][ntp][r], x2 = acc[mt][ntp + 2][r];
                    size_t base = (size_t)(nbase + r) * HD;
                    dst[base + j]      = bf16_1(x1 * cc[r] - x2 * ss[r]);
                    dst[base + j + 32] = bf16_1(x1 * ss[r] + x2 * cc[r]);
                }
            }
        }
    } else {
        unsigned short* dst = vt + (size_t)bh * HD * NN;
#pragma unroll
        for (int mt = 0; mt < 4; ++mt)
#pragma unroll
            for (int nt = 0; nt < 4; ++nt) {
                int d = 16 * nt + qlo;
                int n = n0 + wn + 16 * mt + 4 * quad;
                uint2 u;
                u.x = pk(acc[mt][nt][0], acc[mt][nt][1]);
                u.y = pk(acc[mt][nt][2], acc[mt][nt][3]);
                *(uint2*)(dst + (size_t)d * NN + n) = u;
            }
    }
}

// ------------------------------------------------------- attention (32x32 MFMA)
// Wave owns 64 queries (2 tiles of 32); 128-key LDS staging, two 64-key
// sub-chunks per barrier. Sᵀ=K·Qᵀ in 32×32×16; P stays in registers — the
// Sᵀ C-layout equals the PV A-layout under key-perm π(8h+j)=4h+(j&3)+8(j>>2),
// which is applied to V rows at staging. Softmax sum via MFMA with ones-B.
// LDS: K 128×144B @0, V(perm) 64×272B @18432. XCD-swizzled blocks.
__global__ __launch_bounds__(256, 2) void attn_kernel(
        const unsigned short* __restrict__ qbf, const unsigned short* __restrict__ kbf,
        const unsigned short* __restrict__ vt, unsigned short* __restrict__ aot) {
    __shared__ unsigned char smem[35840];
    const int VB = 18432;
    int t = threadIdx.x;
    int lane = t & 63, w = t >> 6;
    int lo5 = lane & 31, h = lane >> 5;
    int L = blockIdx.x;
    int bh = (L & 7) + 8 * (L >> 7);       // 16 q-blocks of a bh share one XCD
    int qb = (L >> 3) & 15;
    int bb = bh >> 3, hh = bh & 7;
    int n0w = qb * 256 + w * 64;

    // Q B-frags qf[qt][kt]: lane holds Q[query=32qt+lo5][hd=16kt+8h+j]
    U4S8 qf[2][4];
    const unsigned short* qg = qbf + ((size_t)bh * NN + n0w) * HD;
#pragma unroll
    for (int qt = 0; qt < 2; ++qt)
#pragma unroll
        for (int kt = 0; kt < 4; ++kt)
            qf[qt][kt].u = *(const uint4*)(qg + (size_t)(32 * qt + lo5) * 64 + kt * 16 + 8 * h);

    f32x16 O[2][2], lac[2];
#pragma unroll
    for (int i = 0; i < 16; ++i) {
        O[0][0][i] = 0.f; O[0][1][i] = 0.f; O[1][0][i] = 0.f; O[1][1][i] = 0.f;
        lac[0][i] = 0.f; lac[1][i] = 0.f;
    }
    U4S8 ones;
    ones.u = make_uint4(0x3F803F80u, 0x3F803F80u, 0x3F803F80u, 0x3F803F80u);

    const uint4* kg = (const uint4*)kbf + (size_t)bh * NN * 8;     // K row = 8 uint4
    const uint4* vg = (const uint4*)vt  + (size_t)bh * 64 * 512;   // V row = 512 uint4

    int kof[4], vof[4];
    const uint4* kgp[4]; const uint4* vgp[4];
    uint4 kr[4], vr[4];
#pragma unroll
    for (int i = 0; i < 4; ++i) {
        int idx = t + 256 * i;
        kof[i] = (idx >> 3) * 144 + (idx & 7) * 16;
        kgp[i] = kg + (size_t)(idx >> 3) * 8 + (idx & 7);
        int hd = idx >> 4, u = idx & 15;
        vof[i] = VB + hd * 272 + 32 * (u >> 1) + 8 * (u & 1);
        vgp[i] = vg + (size_t)hd * 512 + u;
        kr[i] = kgp[i][0];
        vr[i] = vgp[i][0];
    }

    for (int it = 0; it < 32; ++it) {
        __syncthreads();
#pragma unroll
        for (int i = 0; i < 4; ++i)
            *(uint4*)(smem + kof[i]) = kr[i];
#pragma unroll
        for (int i = 0; i < 4; ++i) {
            *(uint2*)(smem + vof[i])      = make_uint2(vr[i].x, vr[i].y);
            *(uint2*)(smem + vof[i] + 16) = make_uint2(vr[i].z, vr[i].w);
        }
        __syncthreads();
        if (it + 1 < 32) {
#pragma unroll
            for (int i = 0; i < 4; ++i) {
                kr[i] = kgp[i][(size_t)(it + 1) * 1024];
                vr[i] = vgp[i][(size_t)(it + 1) * 16];
            }
        }

#pragma unroll
        for (int sc = 0; sc < 2; ++sc) {
            U4S8 pa[2][4];
#pragma unroll
            for (int mt = 0; mt < 2; ++mt) {
                f32x16 S0 = {0.f,0.f,0.f,0.f,0.f,0.f,0.f,0.f,0.f,0.f,0.f,0.f,0.f,0.f,0.f,0.f};
                f32x16 S1 = {0.f,0.f,0.f,0.f,0.f,0.f,0.f,0.f,0.f,0.f,0.f,0.f,0.f,0.f,0.f,0.f};
                int kbase = 9216 * sc + 4608 * mt + lo5 * 144 + 16 * h;
#pragma unroll
                for (int kt = 0; kt < 4; ++kt) {
                    U4S8 ka;
                    ka.u = *(const uint4*)(smem + kbase + kt * 32);
                    S0 = __builtin_amdgcn_mfma_f32_32x32x16_bf16(ka.s, qf[0][kt].s, S0, 0, 0, 0);
                    S1 = __builtin_amdgcn_mfma_f32_32x32x16_bf16(ka.s, qf[1][kt].s, S1, 0, 0, 0);
                }
#pragma unroll
                for (int gg = 0; gg < 2; ++gg) {
                    int rb = 8 * gg;
                    pa[0][2 * mt + gg].u = make_uint4(
                        pkru(__builtin_amdgcn_exp2f(S0[rb + 0]), __builtin_amdgcn_exp2f(S0[rb + 1])),
                        pkru(__builtin_amdgcn_exp2f(S0[rb + 2]), __builtin_amdgcn_exp2f(S0[rb + 3])),
                        pkru(__builtin_amdgcn_exp2f(S0[rb + 4]), __builtin_amdgcn_exp2f(S0[rb + 5])),
                        pkru(__builtin_amdgcn_exp2f(S0[rb + 6]), __builtin_amdgcn_exp2f(S0[rb + 7])));
                    pa[1][2 * mt + gg].u = make_uint4(
                        pkru(__builtin_amdgcn_exp2f(S1[rb + 0]), __builtin_amdgcn_exp2f(S1[rb + 1])),
                        pkru(__builtin_amdgcn_exp2f(S1[rb + 2]), __builtin_amdgcn_exp2f(S1[rb + 3])),
                        pkru(__builtin_amdgcn_exp2f(S1[rb + 4]), __builtin_amdgcn_exp2f(S1[rb + 5])),
                        pkru(__builtin_amdgcn_exp2f(S1[rb + 6]), __builtin_amdgcn_exp2f(S1[rb + 7])));
                }
            }
            int vbase = VB + lo5 * 272 + 16 * h + 128 * sc;
#pragma unroll
            for (int g = 0; g < 4; ++g) {
                U4S8 vb0, vb1;
                vb0.u = *(const uint4*)(smem + vbase + 32 * g);
                vb1.u = *(const uint4*)(smem + vbase + 8704 + 32 * g);
                lac[0]  = __builtin_amdgcn_mfma_f32_32x32x16_bf16(pa[0][g].s, ones.s, lac[0], 0, 0, 0);
                lac[1]  = __builtin_amdgcn_mfma_f32_32x32x16_bf16(pa[1][g].s, ones.s, lac[1], 0, 0, 0);
                O[0][0] = __builtin_amdgcn_mfma_f32_32x32x16_bf16(pa[0][g].s, vb0.s, O[0][0], 0, 0, 0);
                O[0][1] = __builtin_amdgcn_mfma_f32_32x32x16_bf16(pa[0][g].s, vb1.s, O[0][1], 0, 0, 0);
                O[1][0] = __builtin_amdgcn_mfma_f32_32x32x16_bf16(pa[1][g].s, vb0.s, O[1][0], 0, 0, 0);
                O[1][1] = __builtin_amdgcn_mfma_f32_32x32x16_bf16(pa[1][g].s, vb1.s, O[1][1], 0, 0, 0);
            }
        }
    }

    // ---- epilogue: normalize (lac is element-aligned with O) and write aoT
    __syncthreads();
    unsigned short* Tw = (unsigned short*)(smem + w * 4608);   // 32 rows x 68 shorts
    unsigned short* aob = aot + (size_t)bb * NN * CDIM + hh * 64;
#pragma unroll
    for (int qt = 0; qt < 2; ++qt) {
#pragma unroll
        for (int r = 0; r < 16; ++r) {
            int qrow = (r & 3) + 8 * (r >> 2) + 4 * h;
            float inv = __builtin_amdgcn_rcpf(lac[qt][r]);
            Tw[qrow * 68 + lo5]      = bf16_1(O[qt][0][r] * inv);
            Tw[qrow * 68 + 32 + lo5] = bf16_1(O[qt][1][r] * inv);
        }
        unsigned short* arow = aob + (size_t)(n0w + 32 * qt + (lane >> 1)) * CDIM + (lane & 1) * 8;
#pragma unroll
        for (int rep = 0; rep < 4; ++rep) {
            uint4 u = *(const uint4*)(Tw + (lane >> 1) * 68 + (lane & 1) * 8 + rep * 16);
            *(uint4*)(arow + rep * 16) = u;
        }
    }
}

// ------------------------------------------------------- proj MFMA GEMM
__global__ __launch_bounds__(256, 2) void proj_mfma_kernel(
        const unsigned short* __restrict__ aot, const unsigned short* __restrict__ wp,
        float* __restrict__ out) {
    __shared__ unsigned short smem[8192];
    int t = threadIdx.x;
    int lane = t & 63, w = t >> 6;
    int qlo = lane & 15, quad = lane >> 4;
    int b = blockIdx.z, o0 = blockIdx.y * 128, n0 = blockIdx.x * 128;
    const unsigned short* ab = aot + (size_t)b * NN * CDIM;
    int row = t >> 2, seg = t & 3;
    int wn = (w & 1) * 64, wo = (w >> 1) * 64;

    f32x4 acc[4][4];
#pragma unroll
    for (int i = 0; i < 4; ++i)
#pragma unroll
        for (int j = 0; j < 4; ++j) acc[i][j] = f32x4{0.f, 0.f, 0.f, 0.f};

    for (int k0 = 0; k0 < 512; k0 += 32) {
        __syncthreads();
        load_lds16(ab + (size_t)(n0 + row) * 512 + k0 + seg * 8,        smem + t * 8);
        load_lds16(ab + (size_t)(n0 + 64 + row) * 512 + k0 + seg * 8,   smem + 2048 + t * 8);
        load_lds16(wp + (size_t)(o0 + row) * 512 + k0 + seg * 8,        smem + 4096 + t * 8);
        load_lds16(wp + (size_t)(o0 + 64 + row) * 512 + k0 + seg * 8,   smem + 6144 + t * 8);
        __syncthreads();
        U4S8 af[4], bf[4];
#pragma unroll
        for (int mt = 0; mt < 4; ++mt)
            af[mt].u = *(const uint4*)(smem + (wn + 16 * mt + qlo) * 32 + quad * 8);
#pragma unroll
        for (int nt = 0; nt < 4; ++nt)
            bf[nt].u = *(const uint4*)(smem + 4096 + (wo + 16 * nt + qlo) * 32 + quad * 8);
#pragma unroll
        for (int mt = 0; mt < 4; ++mt)
#pragma unroll
            for (int nt = 0; nt < 4; ++nt)
                acc[mt][nt] = __builtin_amdgcn_mfma_f32_16x16x32_bf16(
                    af[mt].s, bf[nt].s, acc[mt][nt], 0, 0, 0);
    }

    float* ob = out + (size_t)b * CDIM * NN;
#pragma unroll
    for (int mt = 0; mt < 4; ++mt)
#pragma unroll
        for (int nt = 0; nt < 4; ++nt) {
            int o = o0 + wo + 16 * nt + qlo;
            int n = n0 + wn + 16 * mt + 4 * quad;
            *(float4*)(ob + (size_t)o * NN + n) = *(float4*)&acc[mt][nt];
        }
}

// ------------------------------------------------------- launch
extern "C" void kernel_launch(void* const* d_in, const int* in_sizes, int n_in,
                              void* d_out, int out_size, void* d_ws, size_t ws_size,
                              hipStream_t stream) {
    const float* x      = (const float*)d_in[0];
    const float* w_qkv  = (const float*)d_in[1];
    const float* w_proj = (const float*)d_in[2];
    float* out = (float*)d_out;
    unsigned short* ws = (unsigned short*)d_ws;

    unsigned short* xt  = ws;                  // bf16 [b][n][c]
    unsigned short* qbf = xt  + QSZ;           // bf16 [bh][n][d]
    unsigned short* kbf = qbf + QSZ;           // bf16 [bh][n][d]
    unsigned short* vt  = kbf + QSZ;           // bf16 [bh][d][n]
    unsigned short* aot = vt  + QSZ;           // bf16 [b][n][c]
    unsigned short* wqb = aot + QSZ;           // bf16 [1536][512]
    unsigned short* wpb = wqb + 786432;        // bf16 [512][512]
    float* ct = (float*)(wpb + 262144);        // [32][4096]
    float* st = ct + 32 * 4096;

    conv_w_kernel<<<512, 256, 0, stream>>>(w_qkv, w_proj, wqb, wpb);
    rope_table_kernel<<<512, 256, 0, stream>>>(ct, st);
    transpose_x_kernel<<<dim3(64, 8, B_), 256, 0, stream>>>(x, xt);
    qkv_mfma_kernel<<<dim3(32, 12, B_), 256, 0, stream>>>(xt, wqb, qbf, kbf, vt, ct, st);
    attn_kernel<<<512, 256, 0, stream>>>(qbf, kbf, vt, aot);
    proj_mfma_kernel<<<dim3(32, 4, B_), 256, 0, stream>>>(aot, wpb, out);
}

// Round 6
// 301.964 us; speedup vs baseline: 1.0568x; 1.0568x over previous
//
#include <hip/hip_runtime.h>
#include <math.h>

#define B_    4
#define CDIM  512
#define HEADS 8
#define HD    64
#define NN    4096
#define QSZ   ((size_t)B_*HEADS*NN*HD)   // 8388608 elements
// q scale folded with log2(e): 0.125 * 1.4426950408889634
#define SCALE_Q 0.18033688011112042f

typedef __attribute__((ext_vector_type(8))) short short8;   // 8 bf16
typedef __attribute__((ext_vector_type(4))) float f32x4;
union U4S8 { uint4 u; short8 s; };

// RNE fp32 -> bf16
__device__ inline unsigned pk(float a, float b) {
    unsigned ua = __float_as_uint(a), ub = __float_as_uint(b);
    ua += 0x7FFFu + ((ua >> 16) & 1u);
    ub += 0x7FFFu + ((ub >> 16) & 1u);
    return (ua >> 16) | (ub & 0xFFFF0000u);
}
__device__ inline unsigned short bf16_1(float a) {
    unsigned ua = __float_as_uint(a);
    ua += 0x7FFFu + ((ua >> 16) & 1u);
    return (unsigned short)(ua >> 16);
}
// cheap round-half-up pack (positive inputs): 2 adds + 1 v_perm
__device__ inline unsigned pkru(float a, float b) {
    unsigned ua = __float_as_uint(a) + 0x8000u;
    unsigned ub = __float_as_uint(b) + 0x8000u;
    return __builtin_amdgcn_perm(ub, ua, 0x07060302);  // [hi16(ua) | hi16(ub)<<16]
}

__device__ inline void load_lds16(const unsigned short* g, unsigned short* l) {
    __builtin_amdgcn_global_load_lds(
        (const __attribute__((address_space(1))) unsigned int*)g,
        (__attribute__((address_space(3))) unsigned int*)l, 16, 0, 0);
}

// ------------------------------------------------------- weights -> bf16
__global__ void conv_w_kernel(const float* __restrict__ wq, const float* __restrict__ wp,
                              unsigned short* __restrict__ wqb, unsigned short* __restrict__ wpb) {
    int id = blockIdx.x * 256 + threadIdx.x;
    const float* src; unsigned short* dst; size_t off; float sc = 1.0f;
    if (id < 98304) { src = wq; dst = wqb; off = (size_t)id * 8; if (off < 262144) sc = SCALE_Q; }
    else            { src = wp; dst = wpb; off = (size_t)(id - 98304) * 8; }
    float4 a = *(const float4*)(src + off);
    float4 b = *(const float4*)(src + off + 4);
    uint4 u;
    u.x = pk(a.x * sc, a.y * sc); u.y = pk(a.z * sc, a.w * sc);
    u.z = pk(b.x * sc, b.y * sc); u.w = pk(b.z * sc, b.w * sc);
    *(uint4*)(dst + off) = u;
}

// ------------------------------------------------------- rope tables [j][n]
__global__ void rope_table_kernel(float* __restrict__ ct, float* __restrict__ st) {
    int id = blockIdx.x * 256 + threadIdx.x;
    int j = id >> 12, n = id & 4095;
    int i = j & 15;
    float pos = (j < 16) ? (float)(n >> 6) : (float)(n & 63);
    float freq = exp2f(-(float)i * 0.8304820237218406f);  // 10000^(-i/16)
    float ang = pos * freq;
    ct[id] = cosf(ang);
    st[id] = sinf(ang);
}

// ------------------------------------------------------- x transpose+convert
__global__ __launch_bounds__(256) void transpose_x_kernel(
        const float* __restrict__ x, unsigned short* __restrict__ xt) {
    __shared__ unsigned short T[64 * 72];
    int t = threadIdx.x;
    int b = blockIdx.z, c0 = blockIdx.y * 64, n0 = blockIdx.x * 64;
    const float* xb = x + ((size_t)b * CDIM + c0) * NN + n0;
    int crow = t >> 2, nseg = t & 3;
#pragma unroll
    for (int g = 0; g < 4; ++g) {
        float4 f = *(const float4*)(xb + (size_t)crow * NN + nseg * 16 + g * 4);
        int nb = nseg * 16 + g * 4;
        T[(nb + 0) * 72 + crow] = bf16_1(f.x);
        T[(nb + 1) * 72 + crow] = bf16_1(f.y);
        T[(nb + 2) * 72 + crow] = bf16_1(f.z);
        T[(nb + 3) * 72 + crow] = bf16_1(f.w);
    }
    __syncthreads();
    unsigned short* xo = xt + ((size_t)b * NN + n0) * CDIM + c0;
    int nrow = t >> 2, cseg = t & 3;
    uint4 u0 = *(uint4*)(T + nrow * 72 + cseg * 16);
    uint4 u1 = *(uint4*)(T + nrow * 72 + cseg * 16 + 8);
    *(uint4*)(xo + (size_t)nrow * CDIM + cseg * 16)     = u0;
    *(uint4*)(xo + (size_t)nrow * CDIM + cseg * 16 + 8) = u1;
}

// ------------------------------------------------------- qkv MFMA GEMM
__global__ __launch_bounds__(256, 2) void qkv_mfma_kernel(
        const unsigned short* __restrict__ xt, const unsigned short* __restrict__ wq,
        unsigned short* __restrict__ qbf, unsigned short* __restrict__ kbf,
        unsigned short* __restrict__ vt,
        const float* __restrict__ ct, const float* __restrict__ st) {
    __shared__ unsigned short smem[8192];
    int t = threadIdx.x;
    int lane = t & 63, w = t >> 6;
    int qlo = lane & 15, quad = lane >> 4;
    int b = blockIdx.z, o0 = blockIdx.y * 128, n0 = blockIdx.x * 128;
    const unsigned short* xb = xt + (size_t)b * NN * CDIM;
    int row = t >> 2, seg = t & 3;
    int wn = (w & 1) * 64, wo = (w >> 1) * 64;

    f32x4 acc[4][4];
#pragma unroll
    for (int i = 0; i < 4; ++i)
#pragma unroll
        for (int j = 0; j < 4; ++j) acc[i][j] = f32x4{0.f, 0.f, 0.f, 0.f};

    for (int k0 = 0; k0 < 512; k0 += 32) {
        __syncthreads();
        load_lds16(xb + (size_t)(n0 + row) * 512 + k0 + seg * 8,        smem + t * 8);
        load_lds16(xb + (size_t)(n0 + 64 + row) * 512 + k0 + seg * 8,   smem + 2048 + t * 8);
        load_lds16(wq + (size_t)(o0 + row) * 512 + k0 + seg * 8,        smem + 4096 + t * 8);
        load_lds16(wq + (size_t)(o0 + 64 + row) * 512 + k0 + seg * 8,   smem + 6144 + t * 8);
        __syncthreads();
        U4S8 af[4], bf[4];
#pragma unroll
        for (int mt = 0; mt < 4; ++mt)
            af[mt].u = *(const uint4*)(smem + (wn + 16 * mt + qlo) * 32 + quad * 8);
#pragma unroll
        for (int nt = 0; nt < 4; ++nt)
            bf[nt].u = *(const uint4*)(smem + 4096 + (wo + 16 * nt + qlo) * 32 + quad * 8);
#pragma unroll
        for (int mt = 0; mt < 4; ++mt)
#pragma unroll
            for (int nt = 0; nt < 4; ++nt)
                acc[mt][nt] = __builtin_amdgcn_mfma_f32_16x16x32_bf16(
                    af[mt].s, bf[nt].s, acc[mt][nt], 0, 0, 0);
    }

    int og = o0 + wo;
    int s = og >> 9;
    int h = (og & 511) >> 6;
    int bh = b * HEADS + h;
    if (s < 2) {
        unsigned short* dst = (s ? kbf : qbf) + (size_t)bh * NN * HD;
#pragma unroll
        for (int mt = 0; mt < 4; ++mt) {
            int nbase = n0 + wn + 16 * mt + 4 * quad;
#pragma unroll
            for (int ntp = 0; ntp < 2; ++ntp) {
                int j = 16 * ntp + qlo;
                float4 c4 = *(const float4*)(ct + (size_t)j * NN + nbase);
                float4 s4 = *(const float4*)(st + (size_t)j * NN + nbase);
                float cc[4] = {c4.x, c4.y, c4.z, c4.w};
                float ss[4] = {s4.x, s4.y, s4.z, s4.w};
#pragma unroll
                for (int r = 0; r < 4; ++r) {
                    float x1 = acc[mt][ntp][r], x2 = acc[mt][ntp + 2][r];
                    size_t base = (size_t)(nbase + r) * HD;
                    dst[base + j]      = bf16_1(x1 * cc[r] - x2 * ss[r]);
                    dst[base + j + 32] = bf16_1(x1 * ss[r] + x2 * cc[r]);
                }
            }
        }
    } else {
        unsigned short* dst = vt + (size_t)bh * HD * NN;
#pragma unroll
        for (int mt = 0; mt < 4; ++mt)
#pragma unroll
            for (int nt = 0; nt < 4; ++nt) {
                int d = 16 * nt + qlo;
                int n = n0 + wn + 16 * mt + 4 * quad;
                uint2 u;
                u.x = pk(acc[mt][nt][0], acc[mt][nt][1]);
                u.y = pk(acc[mt][nt][2], acc[mt][nt][3]);
                *(uint2*)(dst + (size_t)d * NN + n) = u;
            }
    }
}

// ------------------------------------------------------- attention (16x16 MFMA)
// Wave owns 32 queries (2 tiles); block = 4 waves = 128 queries; 64-key LDS
// chunks. Sᵀ=K·Qᵀ; P stays in registers (C-layout == A-layout under key-perm
// π(8h+j)=... applied to V at staging). exp2 softmax, VALU l.
// XCD-swizzled: 32 q-blocks of one bh land on one XCD (L2-resident K/V).
// 3 waves/SIMD via __launch_bounds__(256,3). LDS 18432 B.
__global__ __launch_bounds__(256, 3) void attn_kernel(
        const unsigned short* __restrict__ qbf, const unsigned short* __restrict__ kbf,
        const unsigned short* __restrict__ vt, unsigned short* __restrict__ aot) {
    __shared__ unsigned char smem[18432];     // K 0..9215 (64x144B), V 9216..18431 (64x144B)
    int t = threadIdx.x;
    int lane = t & 63, w = t >> 6;
    int qlo = lane & 15, quad = lane >> 4;
    int L = blockIdx.x;                       // 0..1023
    int bh = (L & 7) + 8 * (L >> 8);          // 32 q-blocks of a bh share one XCD
    int qb = (L >> 3) & 31;
    int bb = bh >> 3, hh = bh & 7;
    int n0w = qb * 128 + w * 32;

    // Q B-frags qf[qt][kt]: Q[query=16qt+qlo][hd=32kt+8quad+j]
    U4S8 qf[2][2];
    const unsigned short* qg = qbf + ((size_t)bh * NN + n0w) * HD;
#pragma unroll
    for (int qt = 0; qt < 2; ++qt)
#pragma unroll
        for (int kt = 0; kt < 2; ++kt)
            qf[qt][kt].u = *(const uint4*)(qg + (size_t)(16 * qt + qlo) * 64 + 32 * kt + 8 * quad);

    f32x4 O[2][4];                            // O[qt][ht]: query=16qt+4quad+r, hd=16ht+qlo
#pragma unroll
    for (int i = 0; i < 2; ++i)
#pragma unroll
        for (int j = 0; j < 4; ++j) O[i][j] = f32x4{0.f, 0.f, 0.f, 0.f};
    float lx[2] = {0.f, 0.f};
    float ly[2] = {0.f, 0.f};

    const uint4* kg = (const uint4*)kbf + (size_t)bh * NN * 8;
    const uint4* vg = (const uint4*)vt  + (size_t)bh * 64 * 512;

    int rr0 = t >> 3, s8 = t & 7;            // K key-row / V hd-row 0..31 (+32 second)
    int voff = (s8 >> 2) * 64 + (s8 & 1) * 32 + ((s8 >> 1) & 1) * 8;  // key-perm for PV
    uint4 kr0, kr1, vr0, vr1;
    kr0 = kg[(size_t)rr0 * 8 + s8];
    kr1 = kg[(size_t)(32 + rr0) * 8 + s8];
    vr0 = vg[(size_t)rr0 * 512 + s8];
    vr1 = vg[(size_t)(32 + rr0) * 512 + s8];

    for (int c = 0; c < NN / 64; ++c) {
        __syncthreads();
        *(uint4*)(smem + rr0 * 144 + s8 * 16)        = kr0;
        *(uint4*)(smem + (32 + rr0) * 144 + s8 * 16) = kr1;
        *(uint2*)(smem + 9216 + rr0 * 144 + voff)             = make_uint2(vr0.x, vr0.y);
        *(uint2*)(smem + 9216 + rr0 * 144 + voff + 16)        = make_uint2(vr0.z, vr0.w);
        *(uint2*)(smem + 9216 + (32 + rr0) * 144 + voff)      = make_uint2(vr1.x, vr1.y);
        *(uint2*)(smem + 9216 + (32 + rr0) * 144 + voff + 16) = make_uint2(vr1.z, vr1.w);
        __syncthreads();
        if (c + 1 < NN / 64) {
            int m0 = (c + 1) * 64;
            kr0 = kg[(size_t)(m0 + rr0) * 8 + s8];
            kr1 = kg[(size_t)(m0 + 32 + rr0) * 8 + s8];
            vr0 = vg[(size_t)rr0 * 512 + (m0 >> 3) + s8];
            vr1 = vg[(size_t)(32 + rr0) * 512 + (m0 >> 3) + s8];
        }

        // ---- Sᵀ = K · Qᵀ : S[mt][qt], key=16mt+4quad+r, query=qlo
        f32x4 S[4][2];
#pragma unroll
        for (int mt = 0; mt < 4; ++mt)
#pragma unroll
            for (int qt = 0; qt < 2; ++qt) S[mt][qt] = f32x4{0.f, 0.f, 0.f, 0.f};
#pragma unroll
        for (int kt = 0; kt < 2; ++kt) {
            U4S8 ka[4];
#pragma unroll
            for (int mt = 0; mt < 4; ++mt)
                ka[mt].u = *(const uint4*)(smem + (16 * mt + qlo) * 144 + kt * 64 + quad * 16);
#pragma unroll
            for (int qt = 0; qt < 2; ++qt)
#pragma unroll
                for (int mt = 0; mt < 4; ++mt)
                    S[mt][qt] = __builtin_amdgcn_mfma_f32_16x16x32_bf16(
                        ka[mt].s, qf[qt][kt].s, S[mt][qt], 0, 0, 0);
        }

        // ---- exp2 + in-register bf16 P (A-layout under key-perm)
        uint2 pd[2][4];                      // [q-tile][key-tile]
#pragma unroll
        for (int qt = 0; qt < 2; ++qt)
#pragma unroll
            for (int mt = 0; mt < 4; ++mt) {
                f32x4 s4 = S[mt][qt];
                float p0 = __builtin_amdgcn_exp2f(s4[0]);
                float p1 = __builtin_amdgcn_exp2f(s4[1]);
                float p2 = __builtin_amdgcn_exp2f(s4[2]);
                float p3 = __builtin_amdgcn_exp2f(s4[3]);
                lx[qt] += p0 + p2;
                ly[qt] += p1 + p3;
                pd[qt][mt] = make_uint2(pkru(p0, p1), pkru(p2, p3));
            }

        // ---- O += P · V (V LDS rows carry the same key-perm)
#pragma unroll
        for (int kt = 0; kt < 2; ++kt) {
            U4S8 pa[2];
#pragma unroll
            for (int qt = 0; qt < 2; ++qt)
                pa[qt].u = make_uint4(pd[qt][2 * kt].x, pd[qt][2 * kt].y,
                                      pd[qt][2 * kt + 1].x, pd[qt][2 * kt + 1].y);
#pragma unroll
            for (int ht = 0; ht < 4; ++ht) {
                U4S8 vb;
                vb.u = *(const uint4*)(smem + 9216 + (16 * ht + qlo) * 144 + kt * 64 + quad * 16);
#pragma unroll
                for (int qt = 0; qt < 2; ++qt)
                    O[qt][ht] = __builtin_amdgcn_mfma_f32_16x16x32_bf16(
                        pa[qt].s, vb.s, O[qt][ht], 0, 0, 0);
            }
        }
    }

    // ---- finalize
    float linv[2];
#pragma unroll
    for (int qt = 0; qt < 2; ++qt) {
        float l = lx[qt] + ly[qt];
        l += __shfl_xor(l, 16, 64);
        l += __shfl_xor(l, 32, 64);
        linv[qt] = 1.0f / l;
    }
    __syncthreads();                          // staging LDS now reusable
    unsigned short* Tw = (unsigned short*)(smem + w * 4608);  // 16 x 72 elems
    unsigned short* aob = aot + (size_t)bb * NN * CDIM + hh * 64;
#pragma unroll
    for (int qt = 0; qt < 2; ++qt) {
        float iv[4];
#pragma unroll
        for (int r = 0; r < 4; ++r) iv[r] = __shfl(linv[qt], 4 * quad + r, 64);
#pragma unroll
        for (int ht = 0; ht < 4; ++ht)
#pragma unroll
            for (int r = 0; r < 4; ++r)
                Tw[(4 * quad + r) * 72 + 16 * ht + qlo] = bf16_1(O[qt][ht][r] * iv[r]);
        int row = lane >> 2, cseg = lane & 3;
        uint4 u0 = *(uint4*)(Tw + row * 72 + cseg * 16);
        uint4 u1 = *(uint4*)(Tw + row * 72 + cseg * 16 + 8);
        unsigned short* arow = aob + (size_t)(n0w + 16 * qt + row) * CDIM + cseg * 16;
        *(uint4*)(arow)     = u0;
        *(uint4*)(arow + 8) = u1;
    }
}

// ------------------------------------------------------- proj MFMA GEMM
__global__ __launch_bounds__(256, 2) void proj_mfma_kernel(
        const unsigned short* __restrict__ aot, const unsigned short* __restrict__ wp,
        float* __restrict__ out) {
    __shared__ unsigned short smem[8192];
    int t = threadIdx.x;
    int lane = t & 63, w = t >> 6;
    int qlo = lane & 15, quad = lane >> 4;
    int b = blockIdx.z, o0 = blockIdx.y * 128, n0 = blockIdx.x * 128;
    const unsigned short* ab = aot + (size_t)b * NN * CDIM;
    int row = t >> 2, seg = t & 3;
    int wn = (w & 1) * 64, wo = (w >> 1) * 64;

    f32x4 acc[4][4];
#pragma unroll
    for (int i = 0; i < 4; ++i)
#pragma unroll
        for (int j = 0; j < 4; ++j) acc[i][j] = f32x4{0.f, 0.f, 0.f, 0.f};

    for (int k0 = 0; k0 < 512; k0 += 32) {
        __syncthreads();
        load_lds16(ab + (size_t)(n0 + row) * 512 + k0 + seg * 8,        smem + t * 8);
        load_lds16(ab + (size_t)(n0 + 64 + row) * 512 + k0 + seg * 8,   smem + 2048 + t * 8);
        load_lds16(wp + (size_t)(o0 + row) * 512 + k0 + seg * 8,        smem + 4096 + t * 8);
        load_lds16(wp + (size_t)(o0 + 64 + row) * 512 + k0 + seg * 8,   smem + 6144 + t * 8);
        __syncthreads();
        U4S8 af[4], bf[4];
#pragma unroll
        for (int mt = 0; mt < 4; ++mt)
            af[mt].u = *(const uint4*)(smem + (wn + 16 * mt + qlo) * 32 + quad * 8);
#pragma unroll
        for (int nt = 0; nt < 4; ++nt)
            bf[nt].u = *(const uint4*)(smem + 4096 + (wo + 16 * nt + qlo) * 32 + quad * 8);
#pragma unroll
        for (int mt = 0; mt < 4; ++mt)
#pragma unroll
            for (int nt = 0; nt < 4; ++nt)
                acc[mt][nt] = __builtin_amdgcn_mfma_f32_16x16x32_bf16(
                    af[mt].s, bf[nt].s, acc[mt][nt], 0, 0, 0);
    }

    float* ob = out + (size_t)b * CDIM * NN;
#pragma unroll
    for (int mt = 0; mt < 4; ++mt)
#pragma unroll
        for (int nt = 0; nt < 4; ++nt) {
            int o = o0 + wo + 16 * nt + qlo;
            int n = n0 + wn + 16 * mt + 4 * quad;
            *(float4*)(ob + (size_t)o * NN + n) = *(float4*)&acc[mt][nt];
        }
}

// ------------------------------------------------------- launch
extern "C" void kernel_launch(void* const* d_in, const int* in_sizes, int n_in,
                              void* d_out, int out_size, void* d_ws, size_t ws_size,
                              hipStream_t stream) {
    const float* x      = (const float*)d_in[0];
    const float* w_qkv  = (const float*)d_in[1];
    const float* w_proj = (const float*)d_in[2];
    float* out = (float*)d_out;
    unsigned short* ws = (unsigned short*)d_ws;

    unsigned short* xt  = ws;                  // bf16 [b][n][c]
    unsigned short* qbf = xt  + QSZ;           // bf16 [bh][n][d]
    unsigned short* kbf = qbf + QSZ;           // bf16 [bh][n][d]
    unsigned short* vt  = kbf + QSZ;           // bf16 [bh][d][n]
    unsigned short* aot = vt  + QSZ;           // bf16 [b][n][c]
    unsigned short* wqb = aot + QSZ;           // bf16 [1536][512]
    unsigned short* wpb = wqb + 786432;        // bf16 [512][512]
    float* ct = (float*)(wpb + 262144);        // [32][4096]
    float* st = ct + 32 * 4096;

    conv_w_kernel<<<512, 256, 0, stream>>>(w_qkv, w_proj, wqb, wpb);
    rope_table_kernel<<<512, 256, 0, stream>>>(ct, st);
    transpose_x_kernel<<<dim3(64, 8, B_), 256, 0, stream>>>(x, xt);
    qkv_mfma_kernel<<<dim3(32, 12, B_), 256, 0, stream>>>(xt, wqb, qbf, kbf, vt, ct, st);
    attn_kernel<<<1024, 256, 0, stream>>>(qbf, kbf, vt, aot);
    proj_mfma_kernel<<<dim3(32, 4, B_), 256, 0, stream>>>(aot, wpb, out);
}